// Round 13
// baseline (800.690 us; speedup 1.0000x reference)
//
#include <hip/hip_runtime.h>
#include <cstddef>

#define Nn 32
#define Cc 128
#define Tt 128
#define Vv 25
#define BN_INV 0.9999950000374997f

// ---------------- workspace layout (float offsets), max 53,192,000 ----------
// WB (bf16 weights)    @ 0
// QKBF  [n][192][3200] @ 200,000    row-major (att_s reads it)
// S1BF_T [n][3200][128]@ 200,000    (reuse, qk dead) k-contig (s1 flush)
// ATSB  [n][3][t][625] @ 10,030,400
// Y2BF_T [n][3200][384]@ 13,870,400 k-contig (k_eins writes transposed)
// TOUTB_T padded       @ 23,710,000 (13,721,600 sh: 32n x [9600|409600|9600])
// SOUT  fp32           @ 33,531,200 row-major
// ATTB  [n][u][512]    @ 200,000    (reuse after ff_s consumed S1T)
// XBARB_T [n][t][c]    @ 1,300,000  k-contig
// QKT   fp32           @ 1,600,000
// TMPB  [n][512][3200] @ 2,700,000  ROW-MAJOR
// T1BF  [n][128][3200] @ 46,638,400 row-major
// TOUT  fp32           @ 2,700,000  (reuse, TMPB dead)
// !! TOUTBP overlaps Y2T and TMPB ranges -> k_zpad AFTER t1 (R5/R6 lesson).
// HISTORY: R4/R11/R12 = ~710-706us; 7 levers moved counters, not duration.
// Arithmetic: TCN = 10us MFMA / 17us HBM; runs 110us with all counters low
// -> block-lockstep (2 barriers + vmcnt(0)/iter) serializes resident waves
// (m114 barrier-bound regime). R13: gemm_nb = NO-LDS NO-BARRIER GEMM for
// k-contig A&B (s1/ff_s/qkt/TCN): waves load MFMA fragments DIRECTLY from
// global (verified: direct addr == staged slot mapping), 2-deep reg dbuf.
// B re-read 4x per block (per-wave) but L2-resident via XCD swizzle.
// qk/tmp/t1/ff_t keep the R12 LDS path (fp32/row-major B).

typedef __attribute__((ext_vector_type(8))) short bf16x8;
typedef __attribute__((ext_vector_type(4))) short short4v;
typedef __attribute__((ext_vector_type(4))) float f32x4;

__device__ __forceinline__ unsigned short f2bf(float f) {
    union { float f; unsigned u; } x; x.f = f;
    return (unsigned short)((x.u + 0x7FFFu + ((x.u >> 16) & 1u)) >> 16);
}
__device__ __forceinline__ float bf2f(unsigned short s) {
    union { unsigned u; float f; } x; x.u = ((unsigned)s) << 16;
    return x.f;
}

// =====================================================================
// gemm_nb: BARRIER-FREE MFMA GEMM for k-contiguous A and B.
// tile 128(M-slab per block) x 64(N), 4 waves; wave w owns m-frags 2w,2w+1
// and ALL 4 col-frags. Fragments loaded straight from global:
//   afr[i] lane l = A[m0+(2w+i)*16+(l&15)][k0+(l>>4)*8 ..+8]
//   bfr[c] lane l = B[j0+c*16+(l&15)] [k0+(l>>4)*8 ..+8]
// (identical data the old LDS staging delivered — no LDS, no syncthreads).
// 2-deep register double-buffer; compiler pipelines with counted vmcnt.
// M must be a multiple of 128 (s1/ff_s/TCN:128, qkt:256) — no row guards.
// BMODE 6: B k-contig [col][ldb]
// BMODE 7: TCN padded [e][128]: off(k0) = (k0>>7)*3200 + (k0&127), base col-75
// DMODE 0: D/Dbf row-major ; DMODE 1: Dbf [col][128] via LDS-flush (M==128)
// OM: 0 fp32 D only, 1 bf16 Dbf only, 2 both
// XCD swizzle identical to gemm_k.
// =====================================================================
template<int BMODE, int DMODE, int OM>
__global__ __launch_bounds__(256, 4) void gemm_nb(
    const unsigned short* __restrict__ A, const void* __restrict__ Bv,
    float* __restrict__ D, unsigned short* __restrict__ Dbf,
    const float* __restrict__ resp, const float* __restrict__ bias,
    const float* __restrict__ gg, const float* __restrict__ bb,
    int M, int K, int lda, int ldb, int ldd,
    long an_stride, long bn_stride, long dn_stride, long dbfn,
    int gn, int gxn)
{
    __shared__ __attribute__((aligned(16))) short Ot[(DMODE==1) ? 64*136 : 4];

    const int nwg = gridDim.x;
    const int b   = blockIdx.x;
    const int w   = (b & 7)*(nwg >> 3) + (b >> 3);
    const int n   = w / gxn;
    const int rem = w - n*gxn;
    const int mt  = rem / gn;
    const int nt  = rem - mt*gn;
    const int m0 = mt*128;
    const int j0 = nt*64;

    const int tid = threadIdx.x;
    const int wav = tid >> 6, lane = tid & 63;
    const int lq = lane >> 4, l16 = lane & 15;

    const unsigned short* An = A + (size_t)n*an_stride;
    const unsigned short* Bn = (const unsigned short*)Bv + (size_t)n*bn_stride;

    // fragment base pointers (k-offset added per iteration)
    const unsigned short* pa0 = An + (size_t)(m0 + (2*wav+0)*16 + l16)*lda + lq*8;
    const unsigned short* pa1 = An + (size_t)(m0 + (2*wav+1)*16 + l16)*lda + lq*8;
    const unsigned short* pb[4];
    #pragma unroll
    for (int c = 0; c < 4; ++c) {
        const int col = j0 + c*16 + l16;
        pb[c] = (BMODE == 6) ? Bn + (size_t)col*ldb + lq*8
                             : Bn + ((long)col - 75)*128 + lq*8;  // BMODE 7
    }

    f32x4 acc[2][4];
    #pragma unroll
    for (int i = 0; i < 2; ++i)
        #pragma unroll
        for (int c = 0; c < 4; ++c) acc[i][c] = (f32x4){0.f,0.f,0.f,0.f};

#define OFFB(K0) ((BMODE == 6) ? (long)(K0) \
                               : ((long)((K0) >> 7)*3200 + (long)((K0) & 127)))
#define LOADF(K0, A0, A1, BF)                                                  \
    {                                                                          \
        A0 = *(const bf16x8*)(pa0 + (K0));                                     \
        A1 = *(const bf16x8*)(pa1 + (K0));                                     \
        const long ob = OFFB(K0);                                              \
        _Pragma("unroll")                                                      \
        for (int c = 0; c < 4; ++c) BF[c] = *(const bf16x8*)(pb[c] + ob);      \
    }
#define MFMA8(A0, A1, BF)                                                      \
    {                                                                          \
        _Pragma("unroll")                                                      \
        for (int c = 0; c < 4; ++c) {                                          \
            acc[0][c] = __builtin_amdgcn_mfma_f32_16x16x32_bf16(               \
                A0, BF[c], acc[0][c], 0, 0, 0);                                \
            acc[1][c] = __builtin_amdgcn_mfma_f32_16x16x32_bf16(               \
                A1, BF[c], acc[1][c], 0, 0, 0);                                \
        }                                                                      \
    }

    bf16x8 aA0, aA1, bA[4], aB0, aB1, bB[4];
    LOADF(0, aA0, aA1, bA);
    for (int k0 = 0; k0 < K; k0 += 64) {
        if (k0 + 32 < K) LOADF(k0 + 32, aB0, aB1, bB);
        MFMA8(aA0, aA1, bA);
        if (k0 + 64 < K) LOADF(k0 + 64, aA0, aA1, bA);
        if (k0 + 32 < K) MFMA8(aB0, aB1, bB);
    }
#undef OFFB
#undef LOADF
#undef MFMA8

    // ---- epilogues (identical to gemm_k) ----
    if (DMODE == 1) {
        #pragma unroll
        for (int i = 0; i < 2; ++i) {
            const int mbase = (2*wav + i)*16 + lq*4;
            #pragma unroll
            for (int ct = 0; ct < 4; ++ct) {
                const int col = j0 + ct*16 + l16;
                short4v pk;
                #pragma unroll
                for (int r = 0; r < 4; ++r) {
                    const int mg = mbase + r;
                    const size_t addr = (size_t)mg*ldd + col + (size_t)n*dn_stride;
                    float val = acc[i][ct][r] + (bias ? bias[mg] : 0.f);
                    if (gg) {
                        val = val*(gg[mg]*BN_INV) + bb[mg] + resp[addr];
                        val = val > 0.f ? val : 0.1f*val;
                    }
                    if (OM != 1) D[addr] = val;
                    pk[r] = (short)f2bf(val);
                }
                *(short4v*)(Ot + (ct*16 + l16)*136 + mbase) = pk;
            }
        }
        __syncthreads();
        #pragma unroll
        for (int j = 0; j < 4; ++j) {
            int idx = j*256 + tid;
            int cl = idx >> 4, m8 = (idx & 15)*8;
            *(bf16x8*)(Dbf + (size_t)(j0 + cl)*128 + m8 + (size_t)n*dbfn)
                = *(const bf16x8*)(Ot + cl*136 + m8);
        }
    } else {
        #pragma unroll
        for (int i = 0; i < 2; ++i) {
            const int mbase = m0 + (2*wav + i)*16 + lq*4;
            #pragma unroll
            for (int ct = 0; ct < 4; ++ct) {
                const int col = j0 + ct*16 + l16;
                #pragma unroll
                for (int r = 0; r < 4; ++r) {
                    const int mg = mbase + r;
                    const size_t addr = (size_t)mg*ldd + col + (size_t)n*dn_stride;
                    float val = acc[i][ct][r] + (bias ? bias[mg] : 0.f);
                    if (gg) {
                        val = val*(gg[mg]*BN_INV) + bb[mg] + resp[addr];
                        val = val > 0.f ? val : 0.1f*val;
                    }
                    if (OM != 1) D[addr] = val;
                    if (OM >= 1) Dbf[addr] = f2bf(val);
                }
            }
        }
    }
}

// =====================================================================
// gemm_k: R12 LDS-staged GEMM (qk/tmp/t1/ff_t), tile 128x64, BK=32,
// 1-deep reg prefetch, XCD swizzle.
// =====================================================================
#define GFETCH(K0)                                                             \
    {                                                                          \
        int mg = m0 + sm;                                                      \
        if (mg < M) {                                                          \
            const unsigned short* ap = An + (size_t)mg*lda + (K0) + skh*16;    \
            a0n = *(const bf16x8*)ap;                                          \
            a1n = *(const bf16x8*)(ap + 8);                                    \
        }                                                                      \
        if (BMODE == 0) {                                                      \
            const unsigned short* Bn = (const unsigned short*)Bv               \
                                     + (size_t)n*bn_stride;                    \
            _Pragma("unroll")                                                  \
            for (int j = 0; j < 8; ++j)                                        \
                bqn[j] = Bn[(size_t)((K0) + skq*8 + j)*ldb + bcol];            \
        } else if (BMODE == 4) {                                               \
            const float* Bf = (const float*)Bv + (size_t)n*bn_stride;          \
            _Pragma("unroll")                                                  \
            for (int j = 0; j < 8; ++j)                                        \
                bqn[j] = f2bf(Bf[(size_t)((K0) + skq*8 + j)*ldb + bcol]);      \
        } else { /* BMODE 3 */                                                 \
            const unsigned short* Bn = (const unsigned short*)Bv               \
                                     + (size_t)n*bn_stride;                    \
            int kb = (K0) + skq*8;                                             \
            int h = kb >> 7, t0b = kb & 127;                                   \
            const unsigned short* bp = Bn + (size_t)h*409600 + (size_t)bo*3200 \
                                          + (size_t)t0b*25 + bv_;              \
            _Pragma("unroll")                                                  \
            for (int j = 0; j < 8; ++j) bqn[j] = bp[j*25];                     \
        }                                                                      \
    }

template<int BMODE, int DMODE, int OM>
__global__ __launch_bounds__(256, 4) void gemm_k(
    const unsigned short* __restrict__ A, const void* __restrict__ Bv,
    float* __restrict__ D, unsigned short* __restrict__ Dbf,
    const float* __restrict__ resp, const float* __restrict__ bias,
    const float* __restrict__ gg, const float* __restrict__ bb,
    int M, int K, int lda, int ldb, int ldd,
    long an_stride, long bn_stride, long dn_stride, long dbfn,
    int gn, int gxn)
{
    __shared__ short Al[8*64*8];   // 8KB
    __shared__ short Bl[4*64*8];   // 4KB
    __shared__ __attribute__((aligned(16))) short Ot[(DMODE==1) ? 64*136 : 4];

    const int nwg = gridDim.x;
    const int b   = blockIdx.x;
    const int w   = (b & 7)*(nwg >> 3) + (b >> 3);
    const int n   = w / gxn;
    const int rem = w - n*gxn;
    const int mt  = rem / gn;
    const int nt  = rem - mt*gn;
    const int m0 = mt*128;
    const int j0 = nt*64;

    const unsigned short* An = A + (size_t)n*an_stride;

    const int tid = threadIdx.x;
    const int wav = tid >> 6, lane = tid & 63;
    const int lq = lane >> 4, l16 = lane & 15;

    const int sm  = tid >> 1, skh = tid & 1;
    const int scol = tid & 63, skq = tid >> 6;
    const int bcol = j0 + scol;

    int bo = 0, bv_ = 0;
    if (BMODE == 3) { bo = bcol/25; bv_ = bcol - 25*bo; }

    f32x4 acc[2][4];
    #pragma unroll
    for (int i = 0; i < 2; ++i)
        #pragma unroll
        for (int c = 0; c < 4; ++c) acc[i][c] = (f32x4){0.f,0.f,0.f,0.f};

    bf16x8 a0n = (bf16x8){0,0,0,0,0,0,0,0}, a1n = a0n;
    alignas(16) unsigned short bqn[8];
    GFETCH(0);

    for (int k0 = 0; k0 < K; k0 += 32) {
        __syncthreads();
        {
            short* Ap = Al + ((size_t)((sm>>4)*64 + (sm&15) + 32*skh))*8;
            *(bf16x8*)Ap = a0n;
            *(bf16x8*)(Ap + 128) = a1n;
        }
        {
            short* Bp = Bl + ((size_t)((scol>>4)*64 + skq*16 + (scol&15)))*8;
            *(bf16x8*)Bp = *(const bf16x8*)bqn;
        }
        __syncthreads();

        if (k0 + 32 < K) GFETCH(k0 + 32);

        bf16x8 afr[2], bfr[4];
        afr[0] = *(const bf16x8*)(Al + ((size_t)((2*wav+0)*64 + lane))*8);
        afr[1] = *(const bf16x8*)(Al + ((size_t)((2*wav+1)*64 + lane))*8);
        #pragma unroll
        for (int c = 0; c < 4; ++c)
            bfr[c] = *(const bf16x8*)(Bl + ((size_t)(c*64 + lane))*8);
        #pragma unroll
        for (int i = 0; i < 2; ++i)
            #pragma unroll
            for (int c = 0; c < 4; ++c)
                acc[i][c] = __builtin_amdgcn_mfma_f32_16x16x32_bf16(
                    afr[i], bfr[c], acc[i][c], 0, 0, 0);
    }

    if (DMODE == 1) {
        #pragma unroll
        for (int i = 0; i < 2; ++i) {
            const int mbase = (2*wav + i)*16 + lq*4;
            #pragma unroll
            for (int ct = 0; ct < 4; ++ct) {
                const int col = j0 + ct*16 + l16;
                short4v pk;
                #pragma unroll
                for (int r = 0; r < 4; ++r) {
                    const int mg = mbase + r;
                    const size_t addr = (size_t)mg*ldd + col + (size_t)n*dn_stride;
                    float val = acc[i][ct][r] + (bias ? bias[mg] : 0.f);
                    if (gg) {
                        val = val*(gg[mg]*BN_INV) + bb[mg] + resp[addr];
                        val = val > 0.f ? val : 0.1f*val;
                    }
                    if (OM != 1) D[addr] = val;
                    pk[r] = (short)f2bf(val);
                }
                *(short4v*)(Ot + (ct*16 + l16)*136 + mbase) = pk;
            }
        }
        __syncthreads();
        #pragma unroll
        for (int j = 0; j < 4; ++j) {
            int idx = j*256 + tid;
            int cl = idx >> 4, m8 = (idx & 15)*8;
            *(bf16x8*)(Dbf + (size_t)(j0 + cl)*128 + m8 + (size_t)n*dbfn)
                = *(const bf16x8*)(Ot + cl*136 + m8);
        }
    } else {
        #pragma unroll
        for (int i = 0; i < 2; ++i) {
            const int mbase = m0 + (2*wav + i)*16 + lq*4;
            #pragma unroll
            for (int ct = 0; ct < 4; ++ct) {
                const int col = j0 + ct*16 + l16;
                if (DMODE == 0) {
                    #pragma unroll
                    for (int r = 0; r < 4; ++r) {
                        const int mg = mbase + r;
                        if (mg < M) {
                            const size_t addr = (size_t)mg*ldd + col
                                              + (size_t)n*dn_stride;
                            float val = acc[i][ct][r] + (bias ? bias[mg] : 0.f);
                            if (gg) {
                                val = val*(gg[mg]*BN_INV) + bb[mg] + resp[addr];
                                val = val > 0.f ? val : 0.1f*val;
                            }
                            if (OM != 1) D[addr] = val;
                            if (OM >= 1) Dbf[addr] = f2bf(val);
                        }
                    }
                } else { // DMODE 2 (t1, row-major T1BF)
                    const int c = col/25, v = col - 25*c;
                    const float bi = bias ? bias[c] : 0.f;
                    float gv = 0.f, b2 = 0.f;
                    if (gg) { gv = gg[c]*BN_INV; b2 = bb[c]; }
                    #pragma unroll
                    for (int r = 0; r < 4; ++r) {
                        const int u = mbase + r;
                        const size_t addr = (size_t)c*3200 + (size_t)u*25 + v
                                          + (size_t)n*dn_stride;
                        float val = acc[i][ct][r] + bi;
                        if (gg) {
                            val = val*gv + b2 + resp[addr];
                            val = val > 0.f ? val : 0.1f*val;
                        }
                        if (OM != 1) D[addr] = val;
                        if (OM >= 1) Dbf[addr] = f2bf(val);
                    }
                }
            }
        }
    }
}

// weight prep: convert (and permute) all weights to bf16 in WB
__global__ void k_prep(const float* __restrict__ wis, const float* __restrict__ wos,
                       const float* __restrict__ wfs, const float* __restrict__ wit,
                       const float* __restrict__ wot, const float* __restrict__ wft,
                       const float* __restrict__ wtc, unsigned short* __restrict__ W) {
    int i = blockIdx.x*256 + threadIdx.x;
    if (i < 24576) { W[i] = f2bf(wis[i]); return; }          i -= 24576;
    if (i < 49152) { W[24576 + i] = f2bf(wos[i]); return; }  i -= 49152;
    if (i < 16384) { W[73728 + i] = f2bf(wfs[i]); return; }  i -= 16384;
    if (i < 32768) { W[90112 + i] = f2bf(wit[i]); return; }  i -= 32768;
    if (i < 65536) { // [(h*128+o)][c] <- wot[o][h*128+c]
        int ho = i >> 7, c = i & 127; int h = ho >> 7, o = ho & 127;
        W[122880 + i] = f2bf(wot[o*512 + h*128 + c]); return; } i -= 65536;
    if (i < 16384) { W[188416 + i] = f2bf(wft[i]); return; } i -= 16384;
    if (i < 114688) { // [o][kidx*128+c] <- wtc[(o*128+c)*7 + kidx]
        int o = i / 896; int r = i - o*896; int kidx = r >> 7, c = r & 127;
        W[204800 + i] = f2bf(wtc[(o*128 + c)*7 + kidx]); }
}

// zero the TCN pad margins: per n, shorts [0,9600) and [419200,428800).
// MUST run after t1 (TOUTBP overlaps Y2T and TMPB; t1 is last TMPB reader).
__global__ void k_zpad(unsigned short* __restrict__ p) {
    int i = blockIdx.x*256 + threadIdx.x;     // 76800 threads x 8 shorts
    if (i >= 76800) return;
    int chunk = i*8;
    int n = chunk / 19200;
    int r = chunk - n*19200;
    size_t addr = (size_t)n*428800 + (size_t)(r < 9600 ? r : 419200 + (r - 9600));
    *(bf16x8*)(p + addr) = (bf16x8){0,0,0,0,0,0,0,0};
}

// spatial attention: atts_bf = att0 + tanh(q.k/32)*alpha  (reads bf16 qk)
__global__ void k_att_s(const unsigned short* __restrict__ qk,
                        const float* __restrict__ att0,
                        const float* __restrict__ alphas,
                        unsigned short* __restrict__ att) {
    int b = blockIdx.x;
    int n = b / (3*Tt); int rem = b - n*(3*Tt); int s = rem / Tt; int t = rem - s*Tt;
    __shared__ float qs[32*Vv], ks[32*Vv];
    const unsigned short* qp = qk + (size_t)n*614400 + (size_t)(s*32)*3200 + t*25;
    const unsigned short* kp = qk + (size_t)n*614400 + (size_t)(96 + s*32)*3200 + t*25;
    for (int i = threadIdx.x; i < 32*Vv; i += 256) {
        int c = i / Vv, v = i - c*Vv;
        qs[i] = bf2f(qp[(size_t)c*3200 + v]);
        ks[i] = bf2f(kp[(size_t)c*3200 + v]);
    }
    __syncthreads();
    float alpha = alphas[s];
    for (int i = threadIdx.x; i < Vv*Vv; i += 256) {
        int u = i / Vv, v = i - u*Vv;
        float a = 0.f;
        #pragma unroll
        for (int c = 0; c < 32; ++c) a += qs[c*Vv + u] * ks[c*Vv + v];
        att[(size_t)n*240000 + (size_t)s*80000 + (size_t)t*625 + i] =
            f2bf(att0[s*625 + i] + tanhf(a * (1.f/32.f)) * alpha);
    }
}

// =====================================================================
// MFMA spatial einsum -> Y2 TRANSPOSED: y2T[(t*25+v)*384 + s*128 + c]
// =====================================================================
__global__ __launch_bounds__(256, 2) void k_eins_mfma(
    const float* __restrict__ X, const unsigned short* __restrict__ att,
    unsigned short* __restrict__ y2)
{
    __shared__ short Xf[128*128];     // [c][tl*32+u] bf16, swizzled (32KB)
    __shared__ short Bf[7*4*64*8];    // frag [nt][ks][lane][j] (28KB)

    const int n  = blockIdx.x >> 5;
    const int t0 = (blockIdx.x & 31) * 4;
    const int tid = threadIdx.x;
    const int wav = tid >> 6, lane = tid & 63;
    const int lq = lane >> 4, l16 = lane & 15;

    for (int i = tid; i < 7*4*64; i += 256)
        *(bf16x8*)(Bf + (size_t)i*8) = (bf16x8){0,0,0,0,0,0,0,0};

    const float* xp = X + (size_t)n*409600;
    for (int i = tid; i < 8192; i += 256) {
        int u2 = (i & 15)*2, tl = (i >> 4) & 3, c = i >> 6;
        float f0 = 0.f, f1 = 0.f;
        if (u2 < 25) {
            const float* p = xp + (size_t)c*3200 + (t0 + tl)*25 + u2;
            f0 = p[0];
            if (u2 < 24) f1 = p[1];
        }
        unsigned pk = (unsigned)f2bf(f0) | ((unsigned)f2bf(f1) << 16);
        int byte = (i*4) ^ ((c & 7) << 4);
        *(unsigned*)((char*)Xf + byte) = pk;
    }
    __syncthreads();

    bf16x8 afr[2][4];
    #pragma unroll
    for (int i = 0; i < 2; ++i) {
        const int c = (2*wav + i)*16 + l16;
        #pragma unroll
        for (int ks = 0; ks < 4; ++ks) {
            int byte = ((c*128 + ks*32 + lq*8)*2) ^ ((c & 7) << 4);
            afr[i][ks] = *(const bf16x8*)((const char*)Xf + byte);
        }
    }

    for (int s = 0; s < 3; ++s) {
        const unsigned short* ap = att + (size_t)n*240000 + (size_t)s*80000
                                       + (size_t)t0*625;
        for (int j = tid; j < 2500; j += 256) {
            int tl = j / 625, r = j - tl*625;
            int u = r / 25, v = r - u*25;
            int col = tl*25 + v;
            int l = ((u >> 3) << 4) | (col & 15);
            int nt = col >> 4;
            Bf[(size_t)((nt*4 + tl)*64 + l)*8 + (u & 7)] = (short)ap[j];
        }
        __syncthreads();

        f32x4 acc[2][7];
        #pragma unroll
        for (int i = 0; i < 2; ++i)
            #pragma unroll
            for (int nt = 0; nt < 7; ++nt) acc[i][nt] = (f32x4){0.f,0.f,0.f,0.f};

        #pragma unroll
        for (int ks = 0; ks < 4; ++ks) {
            bf16x8 bfr[7];
            #pragma unroll
            for (int nt = 0; nt < 7; ++nt)
                bfr[nt] = *(const bf16x8*)(Bf + (size_t)((nt*4 + ks)*64 + lane)*8);
            #pragma unroll
            for (int i = 0; i < 2; ++i)
                #pragma unroll
                for (int nt = 0; nt < 7; ++nt)
                    acc[i][nt] = __builtin_amdgcn_mfma_f32_16x16x32_bf16(
                        afr[i][ks], bfr[nt], acc[i][nt], 0, 0, 0);
        }

        // transposed write: y2T[(t0*25+col)*384 + s*128 + row..row+3]
        unsigned short* yb = y2 + (size_t)n*1228800;
        #pragma unroll
        for (int i = 0; i < 2; ++i) {
            const int row = (2*wav + i)*16 + lq*4;
            #pragma unroll
            for (int nt = 0; nt < 7; ++nt) {
                const int col = nt*16 + l16;
                if (col < 100) {
                    short4v pk;
                    #pragma unroll
                    for (int r = 0; r < 4; ++r) pk[r] = (short)f2bf(acc[i][nt][r]);
                    *(short4v*)(yb + (size_t)(t0*25 + col)*384 + s*128 + row) = pk;
                }
            }
        }
        __syncthreads();
    }
}

// xbarT[n][t*128 + c] = mean_v sout  (k-contiguous for qkt)
__global__ void k_mean(const float* __restrict__ X, unsigned short* __restrict__ xb) {
    int idx = blockIdx.x*256 + threadIdx.x;
    if (idx >= Nn*Cc*Tt) return;
    const float* p = X + (size_t)idx*25;
    float s = 0.f;
    #pragma unroll
    for (int v = 0; v < Vv; ++v) s += p[v];
    int n = idx >> 14, rem = idx & 16383, c = rem >> 7, t = rem & 127;
    xb[(size_t)n*16384 + (size_t)t*128 + c] = f2bf(s * (1.f/25.f));
}

// temporal attention: attb_bf[n][u][(h*128+t)] = mask*alpha*tanh(dot/32)
__global__ void k_att_t(const float* __restrict__ qkt, const float* __restrict__ af,
                        const float* __restrict__ ab, unsigned short* __restrict__ attb) {
    int n = blockIdx.x >> 2, h = blockIdx.x & 3;
    __shared__ float qs[32*Tt], ks[32*Tt];
    const float* qp = qkt + (size_t)n*32768 + (size_t)(h*32)*128;
    const float* kp = qkt + (size_t)n*32768 + (size_t)(128 + h*32)*128;
    for (int i = threadIdx.x; i < 32*Tt; i += 256) { qs[i] = qp[i]; ks[i] = kp[i]; }
    __syncthreads();
    float alpha = (h < 2) ? af[h] : ab[h-2];
    for (int i = threadIdx.x; i < Tt*Tt; i += 256) {
        int u = i >> 7, t = i & 127;
        bool keep = (h < 2) ? (t >= u) : (t <= u);
        float val = 0.f;
        if (keep) {
            float a = 0.f;
            #pragma unroll
            for (int c = 0; c < 32; ++c) a += qs[c*Tt + t] * ks[c*Tt + u];
            val = tanhf(a * (1.f/32.f)) * alpha;
        }
        attb[(size_t)n*65536 + (size_t)u*512 + h*128 + t] = f2bf(val);
    }
}

extern "C" void kernel_launch(void* const* d_in, const int* in_sizes, int n_in,
                              void* d_out, int out_size, void* d_ws, size_t ws_size,
                              hipStream_t stream) {
    const float* x       = (const float*)d_in[0];
    const float* w_in_s  = (const float*)d_in[1];
    const float* b_in_s  = (const float*)d_in[2];
    const float* att0s   = (const float*)d_in[3];
    const float* alphas  = (const float*)d_in[4];
    const float* w_out_s = (const float*)d_in[5];
    const float* b_out_s = (const float*)d_in[6];
    const float* g_out_s = (const float*)d_in[7];
    const float* be_out_s= (const float*)d_in[8];
    const float* w_ff_s  = (const float*)d_in[9];
    const float* b_ff_s  = (const float*)d_in[10];
    const float* g_ff_s  = (const float*)d_in[11];
    const float* be_ff_s = (const float*)d_in[12];
    const float* w_in_t  = (const float*)d_in[13];
    const float* b_in_t  = (const float*)d_in[14];
    const float* alphat_f= (const float*)d_in[15];
    const float* alphat_b= (const float*)d_in[16];
    const float* w_out_t = (const float*)d_in[17];
    const float* b_out_t = (const float*)d_in[18];
    const float* g_out_t = (const float*)d_in[19];
    const float* be_out_t= (const float*)d_in[20];
    const float* w_ff_t  = (const float*)d_in[21];
    const float* b_ff_t  = (const float*)d_in[22];
    const float* g_ff_t  = (const float*)d_in[23];
    const float* be_ff_t = (const float*)d_in[24];
    const float* w_tcn   = (const float*)d_in[25];
    const float* b_tcn   = (const float*)d_in[26];
    const float* g_tcn   = (const float*)d_in[27];
    const float* be_tcn  = (const float*)d_in[28];

    float* ws = (float*)d_ws;
    unsigned short* WB    = (unsigned short*)ws;
    unsigned short* QKBF  = (unsigned short*)(ws + 200000);
    unsigned short* S1BF  = (unsigned short*)(ws + 200000);   // S1T [col][128]
    unsigned short* ATSB  = (unsigned short*)(ws + 10030400);
    unsigned short* Y2BF  = (unsigned short*)(ws + 13870400); // Y2T [col][384]
    unsigned short* TOUTBP= (unsigned short*)(ws + 23710000); // padded base
    unsigned short* TOUTB = TOUTBP + 9600;                    // e=0 of n=0
    float*          SOUT  = ws + 33531200;
    unsigned short* ATTB  = (unsigned short*)(ws + 200000);
    unsigned short* XBARB = (unsigned short*)(ws + 1300000);  // [t][c]
    float*          QKT   = ws + 1600000;
    unsigned short* TMPB  = (unsigned short*)(ws + 2700000);  // row-major
    unsigned short* T1BF  = (unsigned short*)(ws + 46638400); // row-major
    float*          TOUT  = ws + 2700000;
    float* out = (float*)d_out;

    unsigned short* wbis = WB;
    unsigned short* wbos = WB + 24576;
    unsigned short* wbfs = WB + 73728;
    unsigned short* wbit = WB + 90112;
    unsigned short* wbot = WB + 122880;
    unsigned short* wbft = WB + 188416;
    unsigned short* wbtc = WB + 204800;

    dim3 blk(256);
    const float* NUL = nullptr;

    k_prep<<<1248, blk, 0, stream>>>(w_in_s, w_out_s, w_ff_s, w_in_t,
                                     w_out_t, w_ff_t, w_tcn, WB);

    // ---- spatial ----
    // qk_bf = W_in_s @ x + b  (BMODE4, LDS path) : 3200 blocks
    gemm_k<4,0,1><<<3200, blk, 0, stream>>>(
        wbis, x, nullptr, QKBF, NUL, b_in_s, NUL, NUL,
        192, 128, 128, 3200, 3200, 0L, 409600L, 614400L, 614400L, 50, 100);
    k_att_s<<<Nn*3*Tt, blk, 0, stream>>>(QKBF, att0s, alphas, ATSB);
    k_eins_mfma<<<dim3(Nn*32), blk, 0, stream>>>(x, ATSB, Y2BF);
    // s1T = lrelu(x + bn(W_out_s @ y2T + b))  (BARRIER-FREE, DMODE1 flush)
    gemm_nb<6,1,1><<<1600, blk, 0, stream>>>(
        wbos, Y2BF, nullptr, S1BF, x, b_out_s, g_out_s, be_out_s,
        128, 384, 384, 384, 3200, 0L, 1228800L, 409600L, 409600L, 50, 50);
    // sout = lrelu(x + bn(W_ff_s @ s1T + b))  (BARRIER-FREE)
    gemm_nb<6,0,0><<<1600, blk, 0, stream>>>(
        wbfs, S1BF, SOUT, nullptr, x, b_ff_s, g_ff_s, be_ff_s,
        128, 128, 128, 128, 3200, 0L, 409600L, 409600L, 409600L, 50, 50);

    // ---- temporal ----
    k_mean<<<2048, blk, 0, stream>>>(SOUT, XBARB);
    // qkt = W_in_t @ xbarT + b  (BARRIER-FREE) : 128 blocks
    gemm_nb<6,0,0><<<128, blk, 0, stream>>>(
        wbit, XBARB, QKT, nullptr, NUL, b_in_t, NUL, NUL,
        256, 128, 128, 128, 128, 0L, 16384L, 32768L, 32768L, 2, 4);
    k_att_t<<<Nn*4, blk, 0, stream>>>(QKT, alphat_f, alphat_b, ATTB);
    // tmp_bf row-major = W_out_t_perm @ sout  (BMODE4, LDS path)
    gemm_k<4,0,1><<<6400, blk, 0, stream>>>(
        wbot, SOUT, nullptr, TMPB, NUL, NUL, NUL, NUL,
        512, 128, 128, 3200, 3200, 0L, 409600L, 1638400L, 1638400L, 50, 200);
    // t1_bf row-major = lrelu(sout + bn(att @ tmp + b))  (BMODE3, DMODE2)
    gemm_k<3,2,1><<<1600, blk, 0, stream>>>(
        ATTB, TMPB, nullptr, T1BF, SOUT, b_out_t, g_out_t, be_out_t,
        128, 512, 512, 3200, 3200, 65536L, 1638400L, 409600L, 409600L, 50, 50);
    // TMPB dead -> zero TCN pad margins (TOUTBP overlaps TMPB/Y2T ranges)
    k_zpad<<<300, blk, 0, stream>>>(TOUTBP);
    // tout fp32 + TOUTB_T = lrelu(sout + bn(W_ff_t @ t1 + b)) (DMODE1 OM2)
    gemm_k<0,1,2><<<1600, blk, 0, stream>>>(
        wbft, T1BF, TOUT, TOUTB, SOUT, b_ff_t, g_ff_t, be_ff_t,
        128, 128, 128, 3200, 3200, 0L, 409600L, 409600L, 428800L, 50, 50);

    // ---- TCN ----
    // out = lrelu(tout + bn(conv7 @ toutbT + b))  (BARRIER-FREE, BMODE7)
    gemm_nb<7,0,0><<<1600, blk, 0, stream>>>(
        wbtc, TOUTB, out, nullptr, TOUT, b_tcn, g_tcn, be_tcn,
        128, 896, 896, 0, 3200, 0L, 428800L, 409600L, 409600L, 50, 50);
}

// Round 14
// 647.926 us; speedup vs baseline: 1.2358x; 1.2358x over previous
//
#include <hip/hip_runtime.h>
#include <cstddef>

#define Nn 32
#define Cc 128
#define Tt 128
#define Vv 25
#define BN_INV 0.9999950000374997f

// ---------------- workspace layout (float offsets), max 53,192,000 ----------
// WB (bf16 weights)    @ 0
// QKBF  [n][192][3200] @ 200,000    row-major (att_s reads it)
// ATSB  [n][3][t][625] @ 10,030,400
// Y2BF_T [n][3200][384]@ 13,870,400 k-contig (k_eins writes transposed)
// TOUTB_T padded       @ 23,710,000 (13,721,600 sh: 32n x [9600|409600|9600])
// SOUT  fp32           @ 33,531,200 row-major
// ATTB  [n][u][512]    @ 200,000    (reuse, qk dead)
// XBARB_T [n][t][c]    @ 1,300,000  k-contig
// QKT   fp32           @ 1,600,000
// TMPB  [n][512][3200] @ 2,700,000  ROW-MAJOR
// T1BF  [n][128][3200] @ 46,638,400 row-major
// TOUT  fp32           @ 2,700,000  (reuse, TMPB dead)
// !! TOUTBP overlaps Y2T and TMPB ranges -> k_zpad AFTER t1 (R5/R6 lesson).
// HISTORY: R4/R11/R12 ~706-710us best. R13 gemm_nb (barrier-free direct
// frags) REGRESSED to 800 (16-way per-instruction scatter beats barrier
// cost). KEY R13 OBSERVATION: qk/t1/TCN all ~110us at FETCH~41MB/WRITE~60MB
// regardless of K -> duration tracks BYTES (~950 GB/s), not FLOPs.
// R14: FUSE s1+ff_s (column-local chain): stage-1 = R12 s1 loop; epilogue
// -> bf16 into padded LDS I[64][136]; ONE barrier; stage-2 K=128 with
// A-frags direct from 32KB w_ff (L2-hot) + B-frags from LDS; writes SOUT.
// Deletes ff_s kernel + S1 intermediate (26MB round-trip).

typedef __attribute__((ext_vector_type(8))) short bf16x8;
typedef __attribute__((ext_vector_type(4))) short short4v;
typedef __attribute__((ext_vector_type(4))) float f32x4;

__device__ __forceinline__ unsigned short f2bf(float f) {
    union { float f; unsigned u; } x; x.f = f;
    return (unsigned short)((x.u + 0x7FFFu + ((x.u >> 16) & 1u)) >> 16);
}
__device__ __forceinline__ float bf2f(unsigned short s) {
    union { unsigned u; float f; } x; x.u = ((unsigned)s) << 16;
    return x.f;
}

// =====================================================================
// gemm_k: R12 LDS-staged GEMM, tile 128x64, BK=32, 1-deep reg prefetch,
// XCD swizzle (w = (b&7)*(nwg>>3)+(b>>3); whole n per XCD).
// BMODE 0: bf16 row-major [K][ldb] scalar
// BMODE 3: tein: k=(h,t), col=(o,v): B = Bn[h*409600+o*3200+t*25+v]
// BMODE 4: fp32 row-major [K][ldb], f2bf in regs
// BMODE 6: bf16 k-contig [col][ldb]: one bf16x8 vector load
// BMODE 7: TCN k-contig padded [e][128]: one vector load
// DMODE 0: D/Dbf row-major; DMODE 1: Dbf [col][128] via LDS flush (M==128)
// DMODE 2: t1: m=u, col=(c,v): addr = c*3200+u*25+v
// OM: 0 fp32 D only, 1 bf16 Dbf only, 2 both
// =====================================================================
#define GFETCH(K0)                                                             \
    {                                                                          \
        int mg = m0 + sm;                                                      \
        if (mg < M) {                                                          \
            const unsigned short* ap = An + (size_t)mg*lda + (K0) + skh*16;    \
            a0n = *(const bf16x8*)ap;                                          \
            a1n = *(const bf16x8*)(ap + 8);                                    \
        }                                                                      \
        if (BMODE == 0) {                                                      \
            const unsigned short* Bn = (const unsigned short*)Bv               \
                                     + (size_t)n*bn_stride;                    \
            _Pragma("unroll")                                                  \
            for (int j = 0; j < 8; ++j)                                        \
                bqn[j] = Bn[(size_t)((K0) + skq*8 + j)*ldb + bcol];            \
        } else if (BMODE == 4) {                                               \
            const float* Bf = (const float*)Bv + (size_t)n*bn_stride;          \
            _Pragma("unroll")                                                  \
            for (int j = 0; j < 8; ++j)                                        \
                bqn[j] = f2bf(Bf[(size_t)((K0) + skq*8 + j)*ldb + bcol]);      \
        } else if (BMODE == 3) {                                               \
            const unsigned short* Bn = (const unsigned short*)Bv               \
                                     + (size_t)n*bn_stride;                    \
            int kb = (K0) + skq*8;                                             \
            int h = kb >> 7, t0b = kb & 127;                                   \
            const unsigned short* bp = Bn + (size_t)h*409600 + (size_t)bo*3200 \
                                          + (size_t)t0b*25 + bv_;              \
            _Pragma("unroll")                                                  \
            for (int j = 0; j < 8; ++j) bqn[j] = bp[j*25];                     \
        } else if (BMODE == 6) {                                               \
            const unsigned short* Bn = (const unsigned short*)Bv               \
                                     + (size_t)n*bn_stride;                    \
            *(bf16x8*)bqn = *(const bf16x8*)(Bn + (size_t)bcol*ldb             \
                                             + (K0) + skq*8);                  \
        } else { /* BMODE 7 */                                                 \
            const unsigned short* Bn = (const unsigned short*)Bv               \
                                     + (size_t)n*bn_stride;                    \
            int kb = (K0) + skq*8;                                             \
            int kidx = kb >> 7, c0 = kb & 127;                                 \
            long e = (long)bcol + (long)(kidx - 3)*25;                         \
            *(bf16x8*)bqn = *(const bf16x8*)(Bn + e*128 + c0);                 \
        }                                                                      \
    }

template<int BMODE, int DMODE, int OM>
__global__ __launch_bounds__(256, 4) void gemm_k(
    const unsigned short* __restrict__ A, const void* __restrict__ Bv,
    float* __restrict__ D, unsigned short* __restrict__ Dbf,
    const float* __restrict__ resp, const float* __restrict__ bias,
    const float* __restrict__ gg, const float* __restrict__ bb,
    int M, int K, int lda, int ldb, int ldd,
    long an_stride, long bn_stride, long dn_stride, long dbfn,
    int gn, int gxn)
{
    __shared__ short Al[8*64*8];   // 8KB
    __shared__ short Bl[4*64*8];   // 4KB
    __shared__ __attribute__((aligned(16))) short Ot[(DMODE==1) ? 64*136 : 4];

    const int nwg = gridDim.x;
    const int b   = blockIdx.x;
    const int w   = (b & 7)*(nwg >> 3) + (b >> 3);
    const int n   = w / gxn;
    const int rem = w - n*gxn;
    const int mt  = rem / gn;
    const int nt  = rem - mt*gn;
    const int m0 = mt*128;
    const int j0 = nt*64;

    const unsigned short* An = A + (size_t)n*an_stride;

    const int tid = threadIdx.x;
    const int wav = tid >> 6, lane = tid & 63;
    const int lq = lane >> 4, l16 = lane & 15;

    const int sm  = tid >> 1, skh = tid & 1;
    const int scol = tid & 63, skq = tid >> 6;
    const int bcol = j0 + scol;

    int bo = 0, bv_ = 0;
    if (BMODE == 3) { bo = bcol/25; bv_ = bcol - 25*bo; }

    f32x4 acc[2][4];
    #pragma unroll
    for (int i = 0; i < 2; ++i)
        #pragma unroll
        for (int c = 0; c < 4; ++c) acc[i][c] = (f32x4){0.f,0.f,0.f,0.f};

    bf16x8 a0n = (bf16x8){0,0,0,0,0,0,0,0}, a1n = a0n;
    alignas(16) unsigned short bqn[8];
    GFETCH(0);

    for (int k0 = 0; k0 < K; k0 += 32) {
        __syncthreads();
        {
            short* Ap = Al + ((size_t)((sm>>4)*64 + (sm&15) + 32*skh))*8;
            *(bf16x8*)Ap = a0n;
            *(bf16x8*)(Ap + 128) = a1n;
        }
        {
            short* Bp = Bl + ((size_t)((scol>>4)*64 + skq*16 + (scol&15)))*8;
            *(bf16x8*)Bp = *(const bf16x8*)bqn;
        }
        __syncthreads();

        if (k0 + 32 < K) GFETCH(k0 + 32);

        bf16x8 afr[2], bfr[4];
        afr[0] = *(const bf16x8*)(Al + ((size_t)((2*wav+0)*64 + lane))*8);
        afr[1] = *(const bf16x8*)(Al + ((size_t)((2*wav+1)*64 + lane))*8);
        #pragma unroll
        for (int c = 0; c < 4; ++c)
            bfr[c] = *(const bf16x8*)(Bl + ((size_t)(c*64 + lane))*8);
        #pragma unroll
        for (int i = 0; i < 2; ++i)
            #pragma unroll
            for (int c = 0; c < 4; ++c)
                acc[i][c] = __builtin_amdgcn_mfma_f32_16x16x32_bf16(
                    afr[i], bfr[c], acc[i][c], 0, 0, 0);
    }

    if (DMODE == 1) {
        #pragma unroll
        for (int i = 0; i < 2; ++i) {
            const int mbase = (2*wav + i)*16 + lq*4;
            #pragma unroll
            for (int ct = 0; ct < 4; ++ct) {
                const int col = j0 + ct*16 + l16;
                short4v pk;
                #pragma unroll
                for (int r = 0; r < 4; ++r) {
                    const int mg = mbase + r;
                    const size_t addr = (size_t)mg*ldd + col + (size_t)n*dn_stride;
                    float val = acc[i][ct][r] + (bias ? bias[mg] : 0.f);
                    if (gg) {
                        val = val*(gg[mg]*BN_INV) + bb[mg] + resp[addr];
                        val = val > 0.f ? val : 0.1f*val;
                    }
                    if (OM != 1) D[addr] = val;
                    pk[r] = (short)f2bf(val);
                }
                *(short4v*)(Ot + (ct*16 + l16)*136 + mbase) = pk;
            }
        }
        __syncthreads();
        #pragma unroll
        for (int j = 0; j < 4; ++j) {
            int idx = j*256 + tid;
            int cl = idx >> 4, m8 = (idx & 15)*8;
            *(bf16x8*)(Dbf + (size_t)(j0 + cl)*128 + m8 + (size_t)n*dbfn)
                = *(const bf16x8*)(Ot + cl*136 + m8);
        }
    } else {
        #pragma unroll
        for (int i = 0; i < 2; ++i) {
            const int mbase = m0 + (2*wav + i)*16 + lq*4;
            #pragma unroll
            for (int ct = 0; ct < 4; ++ct) {
                const int col = j0 + ct*16 + l16;
                if (DMODE == 0) {
                    #pragma unroll
                    for (int r = 0; r < 4; ++r) {
                        const int mg = mbase + r;
                        if (mg < M) {
                            const size_t addr = (size_t)mg*ldd + col
                                              + (size_t)n*dn_stride;
                            float val = acc[i][ct][r] + (bias ? bias[mg] : 0.f);
                            if (gg) {
                                val = val*(gg[mg]*BN_INV) + bb[mg] + resp[addr];
                                val = val > 0.f ? val : 0.1f*val;
                            }
                            if (OM != 1) D[addr] = val;
                            if (OM >= 1) Dbf[addr] = f2bf(val);
                        }
                    }
                } else { // DMODE 2 (t1, row-major T1BF)
                    const int c = col/25, v = col - 25*c;
                    const float bi = bias ? bias[c] : 0.f;
                    float gv = 0.f, b2 = 0.f;
                    if (gg) { gv = gg[c]*BN_INV; b2 = bb[c]; }
                    #pragma unroll
                    for (int r = 0; r < 4; ++r) {
                        const int u = mbase + r;
                        const size_t addr = (size_t)c*3200 + (size_t)u*25 + v
                                          + (size_t)n*dn_stride;
                        float val = acc[i][ct][r] + bi;
                        if (gg) {
                            val = val*gv + b2 + resp[addr];
                            val = val > 0.f ? val : 0.1f*val;
                        }
                        if (OM != 1) D[addr] = val;
                        if (OM >= 1) Dbf[addr] = f2bf(val);
                    }
                }
            }
        }
    }
}

// =====================================================================
// k_s1ff: FUSED s1 + ff_s.
// Stage 1 (= R12 s1): acc1 = W_out_s(128x384) @ Y2T cols [j0,j0+64)
//   epilogue: v1 = lrelu(x + bn(acc1+b1))  -> bf16 into I[64 col][136 pad]
// ONE barrier.
// Stage 2: acc2 = W_ff_s(128x128) @ I (B-frags from LDS, A-frags direct
//   from global w_ff (32KB, L2-hot, k-contig rows)).
//   epilogue: SOUT = lrelu(x + bn(acc2+b2))  (fp32 row-major)
// Deletes ff_s kernel + S1 intermediate entirely.
// =====================================================================
__global__ __launch_bounds__(256, 4) void k_s1ff(
    const unsigned short* __restrict__ A1, const unsigned short* __restrict__ B1,
    const unsigned short* __restrict__ A2,
    float* __restrict__ D, const float* __restrict__ xresp,
    const float* __restrict__ b1, const float* __restrict__ g1,
    const float* __restrict__ bb1,
    const float* __restrict__ b2, const float* __restrict__ g2,
    const float* __restrict__ bb2)
{
    __shared__ short Al[8*64*8];   // 8KB
    __shared__ short Bl[4*64*8];   // 4KB
    __shared__ __attribute__((aligned(16))) short Ilds[64*136];  // 17KB

    const int nwg = gridDim.x;       // 1600
    const int b   = blockIdx.x;
    const int w   = (b & 7)*(nwg >> 3) + (b >> 3);
    const int n   = w / 50;
    const int nt  = w - n*50;
    const int j0  = nt*64;

    const int tid = threadIdx.x;
    const int wav = tid >> 6, lane = tid & 63;
    const int lq = lane >> 4, l16 = lane & 15;

    const int sm  = tid >> 1, skh = tid & 1;
    const int scol = tid & 63, skq = tid >> 6;
    const int bcol = j0 + scol;

    const unsigned short* Bn = B1 + (size_t)n*1228800;   // Y2T [3200][384]

    f32x4 acc[2][4];
    #pragma unroll
    for (int i = 0; i < 2; ++i)
        #pragma unroll
        for (int c = 0; c < 4; ++c) acc[i][c] = (f32x4){0.f,0.f,0.f,0.f};

    bf16x8 a0n, a1n;
    alignas(16) unsigned short bqn[8];
    // prologue fetch k=0
    {
        const unsigned short* ap = A1 + (size_t)sm*384 + skh*16;
        a0n = *(const bf16x8*)ap;
        a1n = *(const bf16x8*)(ap + 8);
        *(bf16x8*)bqn = *(const bf16x8*)(Bn + (size_t)bcol*384 + skq*8);
    }

    for (int k0 = 0; k0 < 384; k0 += 32) {
        __syncthreads();
        {
            short* Ap = Al + ((size_t)((sm>>4)*64 + (sm&15) + 32*skh))*8;
            *(bf16x8*)Ap = a0n;
            *(bf16x8*)(Ap + 128) = a1n;
        }
        {
            short* Bp = Bl + ((size_t)((scol>>4)*64 + skq*16 + (scol&15)))*8;
            *(bf16x8*)Bp = *(const bf16x8*)bqn;
        }
        __syncthreads();

        if (k0 + 32 < 384) {
            const unsigned short* ap = A1 + (size_t)sm*384 + (k0+32) + skh*16;
            a0n = *(const bf16x8*)ap;
            a1n = *(const bf16x8*)(ap + 8);
            *(bf16x8*)bqn = *(const bf16x8*)(Bn + (size_t)bcol*384 + (k0+32) + skq*8);
        }

        bf16x8 afr[2], bfr[4];
        afr[0] = *(const bf16x8*)(Al + ((size_t)((2*wav+0)*64 + lane))*8);
        afr[1] = *(const bf16x8*)(Al + ((size_t)((2*wav+1)*64 + lane))*8);
        #pragma unroll
        for (int c = 0; c < 4; ++c)
            bfr[c] = *(const bf16x8*)(Bl + ((size_t)(c*64 + lane))*8);
        #pragma unroll
        for (int i = 0; i < 2; ++i)
            #pragma unroll
            for (int c = 0; c < 4; ++c)
                acc[i][c] = __builtin_amdgcn_mfma_f32_16x16x32_bf16(
                    afr[i], bfr[c], acc[i][c], 0, 0, 0);
    }

    // ---- epilogue 1: s1 value -> Ilds[col][c] (bf16) ----
    __syncthreads();   // Al/Bl done; Ilds region safe (separate array anyway)
    #pragma unroll
    for (int i = 0; i < 2; ++i) {
        const int mbase = (2*wav + i)*16 + lq*4;
        #pragma unroll
        for (int ct = 0; ct < 4; ++ct) {
            const int col = j0 + ct*16 + l16;
            short4v pk;
            #pragma unroll
            for (int r = 0; r < 4; ++r) {
                const int mg = mbase + r;
                const size_t addr = (size_t)mg*3200 + col + (size_t)n*409600;
                float val = acc[i][ct][r] + b1[mg];
                val = val*(g1[mg]*BN_INV) + bb1[mg] + xresp[addr];
                val = val > 0.f ? val : 0.1f*val;
                pk[r] = (short)f2bf(val);
            }
            *(short4v*)(Ilds + (ct*16 + l16)*136 + mbase) = pk;
        }
    }
    __syncthreads();

    // ---- stage 2: acc2 = w_ff (128x128) @ I ----
    f32x4 acc2[2][4];
    #pragma unroll
    for (int i = 0; i < 2; ++i)
        #pragma unroll
        for (int c = 0; c < 4; ++c) acc2[i][c] = (f32x4){0.f,0.f,0.f,0.f};

    #pragma unroll
    for (int k2 = 0; k2 < 128; k2 += 32) {
        bf16x8 a2[2], b2f[4];
        #pragma unroll
        for (int i = 0; i < 2; ++i)
            a2[i] = *(const bf16x8*)(A2 + (size_t)((2*wav+i)*16 + l16)*128
                                        + k2 + lq*8);
        #pragma unroll
        for (int c = 0; c < 4; ++c)
            b2f[c] = *(const bf16x8*)(Ilds + (c*16 + l16)*136 + k2 + lq*8);
        #pragma unroll
        for (int i = 0; i < 2; ++i)
            #pragma unroll
            for (int c = 0; c < 4; ++c)
                acc2[i][c] = __builtin_amdgcn_mfma_f32_16x16x32_bf16(
                    a2[i], b2f[c], acc2[i][c], 0, 0, 0);
    }

    // ---- epilogue 2: SOUT = lrelu(x + bn(acc2 + b2)) ----
    #pragma unroll
    for (int i = 0; i < 2; ++i) {
        const int mbase = (2*wav + i)*16 + lq*4;
        #pragma unroll
        for (int ct = 0; ct < 4; ++ct) {
            const int col = j0 + ct*16 + l16;
            #pragma unroll
            for (int r = 0; r < 4; ++r) {
                const int mg = mbase + r;
                const size_t addr = (size_t)mg*3200 + col + (size_t)n*409600;
                float val = acc2[i][ct][r] + b2[mg];
                val = val*(g2[mg]*BN_INV) + bb2[mg] + xresp[addr];
                val = val > 0.f ? val : 0.1f*val;
                D[addr] = val;
            }
        }
    }
}

// weight prep: convert (and permute) all weights to bf16 in WB
__global__ void k_prep(const float* __restrict__ wis, const float* __restrict__ wos,
                       const float* __restrict__ wfs, const float* __restrict__ wit,
                       const float* __restrict__ wot, const float* __restrict__ wft,
                       const float* __restrict__ wtc, unsigned short* __restrict__ W) {
    int i = blockIdx.x*256 + threadIdx.x;
    if (i < 24576) { W[i] = f2bf(wis[i]); return; }          i -= 24576;
    if (i < 49152) { W[24576 + i] = f2bf(wos[i]); return; }  i -= 49152;
    if (i < 16384) { W[73728 + i] = f2bf(wfs[i]); return; }  i -= 16384;
    if (i < 32768) { W[90112 + i] = f2bf(wit[i]); return; }  i -= 32768;
    if (i < 65536) { // [(h*128+o)][c] <- wot[o][h*128+c]
        int ho = i >> 7, c = i & 127; int h = ho >> 7, o = ho & 127;
        W[122880 + i] = f2bf(wot[o*512 + h*128 + c]); return; } i -= 65536;
    if (i < 16384) { W[188416 + i] = f2bf(wft[i]); return; } i -= 16384;
    if (i < 114688) { // [o][kidx*128+c] <- wtc[(o*128+c)*7 + kidx]
        int o = i / 896; int r = i - o*896; int kidx = r >> 7, c = r & 127;
        W[204800 + i] = f2bf(wtc[(o*128 + c)*7 + kidx]); }
}

// zero the TCN pad margins: per n, shorts [0,9600) and [419200,428800).
// MUST run after t1 (TOUTBP overlaps Y2T and TMPB; t1 is last TMPB reader).
__global__ void k_zpad(unsigned short* __restrict__ p) {
    int i = blockIdx.x*256 + threadIdx.x;     // 76800 threads x 8 shorts
    if (i >= 76800) return;
    int chunk = i*8;
    int n = chunk / 19200;
    int r = chunk - n*19200;
    size_t addr = (size_t)n*428800 + (size_t)(r < 9600 ? r : 419200 + (r - 9600));
    *(bf16x8*)(p + addr) = (bf16x8){0,0,0,0,0,0,0,0};
}

// spatial attention: atts_bf = att0 + tanh(q.k/32)*alpha  (reads bf16 qk)
__global__ void k_att_s(const unsigned short* __restrict__ qk,
                        const float* __restrict__ att0,
                        const float* __restrict__ alphas,
                        unsigned short* __restrict__ att) {
    int b = blockIdx.x;
    int n = b / (3*Tt); int rem = b - n*(3*Tt); int s = rem / Tt; int t = rem - s*Tt;
    __shared__ float qs[32*Vv], ks[32*Vv];
    const unsigned short* qp = qk + (size_t)n*614400 + (size_t)(s*32)*3200 + t*25;
    const unsigned short* kp = qk + (size_t)n*614400 + (size_t)(96 + s*32)*3200 + t*25;
    for (int i = threadIdx.x; i < 32*Vv; i += 256) {
        int c = i / Vv, v = i - c*Vv;
        qs[i] = bf2f(qp[(size_t)c*3200 + v]);
        ks[i] = bf2f(kp[(size_t)c*3200 + v]);
    }
    __syncthreads();
    float alpha = alphas[s];
    for (int i = threadIdx.x; i < Vv*Vv; i += 256) {
        int u = i / Vv, v = i - u*Vv;
        float a = 0.f;
        #pragma unroll
        for (int c = 0; c < 32; ++c) a += qs[c*Vv + u] * ks[c*Vv + v];
        att[(size_t)n*240000 + (size_t)s*80000 + (size_t)t*625 + i] =
            f2bf(att0[s*625 + i] + tanhf(a * (1.f/32.f)) * alpha);
    }
}

// =====================================================================
// MFMA spatial einsum -> Y2 TRANSPOSED: y2T[(t*25+v)*384 + s*128 + c]
// =====================================================================
__global__ __launch_bounds__(256, 2) void k_eins_mfma(
    const float* __restrict__ X, const unsigned short* __restrict__ att,
    unsigned short* __restrict__ y2)
{
    __shared__ short Xf[128*128];     // [c][tl*32+u] bf16, swizzled (32KB)
    __shared__ short Bf[7*4*64*8];    // frag [nt][ks][lane][j] (28KB)

    const int n  = blockIdx.x >> 5;
    const int t0 = (blockIdx.x & 31) * 4;
    const int tid = threadIdx.x;
    const int wav = tid >> 6, lane = tid & 63;
    const int lq = lane >> 4, l16 = lane & 15;

    for (int i = tid; i < 7*4*64; i += 256)
        *(bf16x8*)(Bf + (size_t)i*8) = (bf16x8){0,0,0,0,0,0,0,0};

    const float* xp = X + (size_t)n*409600;
    for (int i = tid; i < 8192; i += 256) {
        int u2 = (i & 15)*2, tl = (i >> 4) & 3, c = i >> 6;
        float f0 = 0.f, f1 = 0.f;
        if (u2 < 25) {
            const float* p = xp + (size_t)c*3200 + (t0 + tl)*25 + u2;
            f0 = p[0];
            if (u2 < 24) f1 = p[1];
        }
        unsigned pk = (unsigned)f2bf(f0) | ((unsigned)f2bf(f1) << 16);
        int byte = (i*4) ^ ((c & 7) << 4);
        *(unsigned*)((char*)Xf + byte) = pk;
    }
    __syncthreads();

    bf16x8 afr[2][4];
    #pragma unroll
    for (int i = 0; i < 2; ++i) {
        const int c = (2*wav + i)*16 + l16;
        #pragma unroll
        for (int ks = 0; ks < 4; ++ks) {
            int byte = ((c*128 + ks*32 + lq*8)*2) ^ ((c & 7) << 4);
            afr[i][ks] = *(const bf16x8*)((const char*)Xf + byte);
        }
    }

    for (int s = 0; s < 3; ++s) {
        const unsigned short* ap = att + (size_t)n*240000 + (size_t)s*80000
                                       + (size_t)t0*625;
        for (int j = tid; j < 2500; j += 256) {
            int tl = j / 625, r = j - tl*625;
            int u = r / 25, v = r - u*25;
            int col = tl*25 + v;
            int l = ((u >> 3) << 4) | (col & 15);
            int nt = col >> 4;
            Bf[(size_t)((nt*4 + tl)*64 + l)*8 + (u & 7)] = (short)ap[j];
        }
        __syncthreads();

        f32x4 acc[2][7];
        #pragma unroll
        for (int i = 0; i < 2; ++i)
            #pragma unroll
            for (int nt = 0; nt < 7; ++nt) acc[i][nt] = (f32x4){0.f,0.f,0.f,0.f};

        #pragma unroll
        for (int ks = 0; ks < 4; ++ks) {
            bf16x8 bfr[7];
            #pragma unroll
            for (int nt = 0; nt < 7; ++nt)
                bfr[nt] = *(const bf16x8*)(Bf + (size_t)((nt*4 + ks)*64 + lane)*8);
            #pragma unroll
            for (int i = 0; i < 2; ++i)
                #pragma unroll
                for (int nt = 0; nt < 7; ++nt)
                    acc[i][nt] = __builtin_amdgcn_mfma_f32_16x16x32_bf16(
                        afr[i][ks], bfr[nt], acc[i][nt], 0, 0, 0);
        }

        // transposed write: y2T[(t0*25+col)*384 + s*128 + row..row+3]
        unsigned short* yb = y2 + (size_t)n*1228800;
        #pragma unroll
        for (int i = 0; i < 2; ++i) {
            const int row = (2*wav + i)*16 + lq*4;
            #pragma unroll
            for (int nt = 0; nt < 7; ++nt) {
                const int col = nt*16 + l16;
                if (col < 100) {
                    short4v pk;
                    #pragma unroll
                    for (int r = 0; r < 4; ++r) pk[r] = (short)f2bf(acc[i][nt][r]);
                    *(short4v*)(yb + (size_t)(t0*25 + col)*384 + s*128 + row) = pk;
                }
            }
        }
        __syncthreads();
    }
}

// xbarT[n][t*128 + c] = mean_v sout  (k-contiguous for qkt)
__global__ void k_mean(const float* __restrict__ X, unsigned short* __restrict__ xb) {
    int idx = blockIdx.x*256 + threadIdx.x;
    if (idx >= Nn*Cc*Tt) return;
    const float* p = X + (size_t)idx*25;
    float s = 0.f;
    #pragma unroll
    for (int v = 0; v < Vv; ++v) s += p[v];
    int n = idx >> 14, rem = idx & 16383, c = rem >> 7, t = rem & 127;
    xb[(size_t)n*16384 + (size_t)t*128 + c] = f2bf(s * (1.f/25.f));
}

// temporal attention: attb_bf[n][u][(h*128+t)] = mask*alpha*tanh(dot/32)
__global__ void k_att_t(const float* __restrict__ qkt, const float* __restrict__ af,
                        const float* __restrict__ ab, unsigned short* __restrict__ attb) {
    int n = blockIdx.x >> 2, h = blockIdx.x & 3;
    __shared__ float qs[32*Tt], ks[32*Tt];
    const float* qp = qkt + (size_t)n*32768 + (size_t)(h*32)*128;
    const float* kp = qkt + (size_t)n*32768 + (size_t)(128 + h*32)*128;
    for (int i = threadIdx.x; i < 32*Tt; i += 256) { qs[i] = qp[i]; ks[i] = kp[i]; }
    __syncthreads();
    float alpha = (h < 2) ? af[h] : ab[h-2];
    for (int i = threadIdx.x; i < Tt*Tt; i += 256) {
        int u = i >> 7, t = i & 127;
        bool keep = (h < 2) ? (t >= u) : (t <= u);
        float val = 0.f;
        if (keep) {
            float a = 0.f;
            #pragma unroll
            for (int c = 0; c < 32; ++c) a += qs[c*Tt + t] * ks[c*Tt + u];
            val = tanhf(a * (1.f/32.f)) * alpha;
        }
        attb[(size_t)n*65536 + (size_t)u*512 + h*128 + t] = f2bf(val);
    }
}

extern "C" void kernel_launch(void* const* d_in, const int* in_sizes, int n_in,
                              void* d_out, int out_size, void* d_ws, size_t ws_size,
                              hipStream_t stream) {
    const float* x       = (const float*)d_in[0];
    const float* w_in_s  = (const float*)d_in[1];
    const float* b_in_s  = (const float*)d_in[2];
    const float* att0s   = (const float*)d_in[3];
    const float* alphas  = (const float*)d_in[4];
    const float* w_out_s = (const float*)d_in[5];
    const float* b_out_s = (const float*)d_in[6];
    const float* g_out_s = (const float*)d_in[7];
    const float* be_out_s= (const float*)d_in[8];
    const float* w_ff_s  = (const float*)d_in[9];
    const float* b_ff_s  = (const float*)d_in[10];
    const float* g_ff_s  = (const float*)d_in[11];
    const float* be_ff_s = (const float*)d_in[12];
    const float* w_in_t  = (const float*)d_in[13];
    const float* b_in_t  = (const float*)d_in[14];
    const float* alphat_f= (const float*)d_in[15];
    const float* alphat_b= (const float*)d_in[16];
    const float* w_out_t = (const float*)d_in[17];
    const float* b_out_t = (const float*)d_in[18];
    const float* g_out_t = (const float*)d_in[19];
    const float* be_out_t= (const float*)d_in[20];
    const float* w_ff_t  = (const float*)d_in[21];
    const float* b_ff_t  = (const float*)d_in[22];
    const float* g_ff_t  = (const float*)d_in[23];
    const float* be_ff_t = (const float*)d_in[24];
    const float* w_tcn   = (const float*)d_in[25];
    const float* b_tcn   = (const float*)d_in[26];
    const float* g_tcn   = (const float*)d_in[27];
    const float* be_tcn  = (const float*)d_in[28];

    float* ws = (float*)d_ws;
    unsigned short* WB    = (unsigned short*)ws;
    unsigned short* QKBF  = (unsigned short*)(ws + 200000);
    unsigned short* ATSB  = (unsigned short*)(ws + 10030400);
    unsigned short* Y2BF  = (unsigned short*)(ws + 13870400); // Y2T [col][384]
    unsigned short* TOUTBP= (unsigned short*)(ws + 23710000); // padded base
    unsigned short* TOUTB = TOUTBP + 9600;                    // e=0 of n=0
    float*          SOUT  = ws + 33531200;
    unsigned short* ATTB  = (unsigned short*)(ws + 200000);
    unsigned short* XBARB = (unsigned short*)(ws + 1300000);  // [t][c]
    float*          QKT   = ws + 1600000;
    unsigned short* TMPB  = (unsigned short*)(ws + 2700000);  // row-major
    unsigned short* T1BF  = (unsigned short*)(ws + 46638400); // row-major
    float*          TOUT  = ws + 2700000;
    float* out = (float*)d_out;

    unsigned short* wbis = WB;
    unsigned short* wbos = WB + 24576;
    unsigned short* wbfs = WB + 73728;
    unsigned short* wbit = WB + 90112;
    unsigned short* wbot = WB + 122880;
    unsigned short* wbft = WB + 188416;
    unsigned short* wbtc = WB + 204800;

    dim3 blk(256);
    const float* NUL = nullptr;

    k_prep<<<1248, blk, 0, stream>>>(w_in_s, w_out_s, w_ff_s, w_in_t,
                                     w_out_t, w_ff_t, w_tcn, WB);

    // ---- spatial ----
    // qk_bf = W_in_s @ x + b  (BMODE4, LDS path) : 3200 blocks
    gemm_k<4,0,1><<<3200, blk, 0, stream>>>(
        wbis, x, nullptr, QKBF, NUL, b_in_s, NUL, NUL,
        192, 128, 128, 3200, 3200, 0L, 409600L, 614400L, 614400L, 50, 100);
    k_att_s<<<Nn*3*Tt, blk, 0, stream>>>(QKBF, att0s, alphas, ATSB);
    k_eins_mfma<<<dim3(Nn*32), blk, 0, stream>>>(x, ATSB, Y2BF);
    // FUSED s1+ff_s -> SOUT  (deletes ff_s kernel + S1 round-trip)
    k_s1ff<<<1600, blk, 0, stream>>>(
        wbos, Y2BF, wbfs, SOUT, x,
        b_out_s, g_out_s, be_out_s, b_ff_s, g_ff_s, be_ff_s);

    // ---- temporal ----
    k_mean<<<2048, blk, 0, stream>>>(SOUT, XBARB);
    // qkt = W_in_t @ xbarT + b  (BMODE6 vec) : 128 blocks
    gemm_k<6,0,0><<<128, blk, 0, stream>>>(
        wbit, XBARB, QKT, nullptr, NUL, b_in_t, NUL, NUL,
        256, 128, 128, 128, 128, 0L, 16384L, 32768L, 32768L, 2, 4);
    k_att_t<<<Nn*4, blk, 0, stream>>>(QKT, alphat_f, alphat_b, ATTB);
    // tmp_bf row-major = W_out_t_perm @ sout  (BMODE4, LDS path)
    gemm_k<4,0,1><<<6400, blk, 0, stream>>>(
        wbot, SOUT, nullptr, TMPB, NUL, NUL, NUL, NUL,
        512, 128, 128, 3200, 3200, 0L, 409600L, 1638400L, 1638400L, 50, 200);
    // t1_bf row-major = lrelu(sout + bn(att @ tmp + b))  (BMODE3, DMODE2)
    gemm_k<3,2,1><<<1600, blk, 0, stream>>>(
        ATTB, TMPB, nullptr, T1BF, SOUT, b_out_t, g_out_t, be_out_t,
        128, 512, 512, 3200, 3200, 65536L, 1638400L, 409600L, 409600L, 50, 50);
    // TMPB dead -> zero TCN pad margins (TOUTBP overlaps TMPB/Y2T ranges)
    k_zpad<<<300, blk, 0, stream>>>(TOUTBP);
    // tout fp32 + TOUTB_T = lrelu(sout + bn(W_ff_t @ t1 + b)) (DMODE1 OM2)
    gemm_k<0,1,2><<<1600, blk, 0, stream>>>(
        wbft, T1BF, TOUT, TOUTB, SOUT, b_ff_t, g_ff_t, be_ff_t,
        128, 128, 128, 3200, 3200, 0L, 409600L, 409600L, 428800L, 50, 50);

    // ---- TCN ----
    // out = lrelu(tout + bn(conv7 @ toutbT + b))  (BMODE7 vec, padded)
    gemm_k<7,0,0><<<1600, blk, 0, stream>>>(
        wbtc, TOUTB, out, nullptr, TOUT, b_tcn, g_tcn, be_tcn,
        128, 896, 896, 0, 3200, 0L, 428800L, 409600L, 409600L, 50, 50);
}